// Round 12
// baseline (2779.496 us; speedup 1.0000x reference)
//
#include <hip/hip_runtime.h>

#define D 128
#define BW_LOG 6          // 64 nodes per bucket
#define BWID 64
#define CAP 4096          // max edges per bucket in LDS (mean ~2048, max ~2350)
#define CHUNK 4096        // edges per partition block (391 blocks -> occupancy)
#define NB_MAX 1024       // supports N <= 65536 (also required by 16-bit src packing)
#define NSLAB 4           // x-table slabs for GPU-phase L2-resident gather

typedef unsigned short u16;
typedef unsigned int u32;
typedef __attribute__((ext_vector_type(8))) short bf16x8;      // 8 bf16 (4 VGPRs)
typedef __attribute__((ext_vector_type(8))) unsigned short u16x8;
typedef __attribute__((ext_vector_type(4))) float f32x4;

__device__ __forceinline__ float bf2f(u16 h) { return __uint_as_float(((u32)h) << 16); }
__device__ __forceinline__ u16 f2bf(float f) {
    u32 u = __float_as_uint(f);
    u32 r = (u + 0x7fffu + ((u >> 16) & 1u)) >> 16;   // RNE
    return (u16)r;
}

// ---------- fused prep: cvt_x + cvt_w + part_hist in one block-partitioned launch ----------

__global__ __launch_bounds__(256)
void prep_kernel(const float* __restrict__ x, u16* __restrict__ xb, int n4,
                 const float* __restrict__ W1l, const float* __restrict__ W1r,
                 const float* __restrict__ W2l, const float* __restrict__ W2r,
                 u16* __restrict__ wc1, u16* __restrict__ wc2,
                 const int* __restrict__ dst, int* __restrict__ gh,
                 int E, int nb, int nblk, int xblk) {
    __shared__ int h[NB_MAX];
    int b = blockIdx.x;
    int t = threadIdx.x;
    if (b < xblk) {
        int i = b * 256 + t;
        if (i < n4) {
            float4 v = ((const float4*)x)[i];
            ushort4 o;
            o.x = f2bf(v.x); o.y = f2bf(v.y); o.z = f2bf(v.z); o.w = f2bf(v.w);
            ((ushort4*)xb)[i] = o;
        }
        return;
    }
    if (b < xblk + 256) {
        int wb = b - xblk;
        int n = wb & 127;
        const float* Wl = (wb < 128) ? W1l : W2l;
        const float* Wr = (wb < 128) ? W1r : W2r;
        u16* wcat = (wb < 128) ? wc1 : wc2;
        float v = (t < 128) ? Wl[n * 128 + t] : Wr[n * 128 + t - 128];
        wcat[n * 256 + t] = f2bf(v);
        return;
    }
    int hb = b - xblk - 256;
    for (int i = t; i < nb; i += 256) h[i] = 0;
    __syncthreads();
    int lo = hb * CHUNK, hi = min(lo + CHUNK, E);
    for (int i = lo + t; i < hi; i += 256) atomicAdd(&h[dst[i] >> BW_LOG], 1);
    __syncthreads();
    for (int i = t; i < nb; i += 256) gh[(size_t)i * nblk + hb] = h[i];
}

// ---------- CSR build ----------

__global__ __launch_bounds__(64)
void part_scan1_kernel(int* __restrict__ gh, int* __restrict__ btot, int nblk) {
    int k = blockIdx.x;
    int t = threadIdx.x;
    int* row = gh + (size_t)k * nblk;
    int chunk = (nblk + 63) >> 6;
    int lo = t * chunk, hi = min(lo + chunk, nblk);
    int s = 0;
    for (int i = lo; i < hi; ++i) s += row[i];
    int incl = s;
#pragma unroll
    for (int d2 = 1; d2 < 64; d2 <<= 1) { int u = __shfl_up(incl, d2, 64); if (t >= d2) incl += u; }
    int excl = incl - s;
    for (int i = lo; i < hi; ++i) { int c = row[i]; row[i] = excl; excl += c; }
    if (t == 63) btot[k] = incl;
}

__global__ __launch_bounds__(1024)
void part_scan2_kernel(const int* __restrict__ btot, int* __restrict__ bbase,
                       int nb, int* __restrict__ offN) {
    __shared__ int ws[16];
    int t = threadIdx.x, lane = t & 63, wid = t >> 6;
    int v = (t < nb) ? btot[t] : 0;
    int incl = v;
#pragma unroll
    for (int d2 = 1; d2 < 64; d2 <<= 1) { int u = __shfl_up(incl, d2, 64); if (lane >= d2) incl += u; }
    if (lane == 63) ws[wid] = incl;
    __syncthreads();
    if (wid == 0) {
        int w = (lane < 16) ? ws[lane] : 0;
#pragma unroll
        for (int d2 = 1; d2 < 16; d2 <<= 1) { int u = __shfl_up(w, d2, 64); if (lane >= d2) w += u; }
        if (lane < 16) ws[lane] = w;
    }
    __syncthreads();
    int base = wid ? ws[wid - 1] : 0;
    int excl = base + incl - v;
    if (t < nb) bbase[t] = excl;
    if (t == nb - 1) { bbase[nb] = excl + v; *offN = excl + v; }
}

// record = (dst_local << 16) | src   (src < 65536)
__global__ __launch_bounds__(256)
void part_scatter_kernel(const int* __restrict__ src, const int* __restrict__ dst,
                         const int* __restrict__ gh, const int* __restrict__ bbase,
                         u32* __restrict__ ebuf, int E, int nb, int nblk) {
    __shared__ int cur[NB_MAX];
    int b = blockIdx.x;
    for (int i = threadIdx.x; i < nb; i += 256)
        cur[i] = bbase[i] + gh[(size_t)i * nblk + b];
    __syncthreads();
    int lo = b * CHUNK, hi = min(lo + CHUNK, E);
    for (int i = lo + threadIdx.x; i < hi; i += 256) {
        int d = dst[i];
        int p = atomicAdd(&cur[d >> BW_LOG], 1);
        ebuf[p] = ((u32)(d & (BWID - 1)) << 16) | (u32)src[i];
    }
}

// one block per bucket: LDS counting sort by key = slab*64 + dst_local (slab-major).
// Keeps full (dl<<16)|src records; emits off2[b*4+s] segment bases and deg[node].
__global__ __launch_bounds__(256)
void bucket_sort_kernel(u32* __restrict__ ebuf, const int* __restrict__ bbase,
                        int* __restrict__ off2, int* __restrict__ deg,
                        int n_nodes, int sw) {
    __shared__ u32 in_s[CAP];
    __shared__ u32 out_s[CAP];
    __shared__ int hist[BWID * NSLAB], cur[BWID * NSLAB];
    __shared__ int wsum[4];
    int b = blockIdx.x;
    int base = bbase[b];
    int n_b = bbase[b + 1] - base;
    int t = threadIdx.x;
    hist[t] = 0;
    for (int i = t; i < n_b && i < CAP; i += 256) in_s[i] = ebuf[base + i];
    __syncthreads();
    for (int i = t; i < n_b && i < CAP; i += 256) {
        u32 v = in_s[i];
        int key = (int)((v & 0xffffu) / (u32)sw) * BWID + (int)(v >> 16);
        atomicAdd(&hist[key], 1);
    }
    __syncthreads();
    {
        int sv = hist[t];
        int lane = t & 63, w = t >> 6;
        int incl = sv;
#pragma unroll
        for (int d2 = 1; d2 < 64; d2 <<= 1) { int u = __shfl_up(incl, d2, 64); if (lane >= d2) incl += u; }
        if (lane == 63) wsum[w] = incl;
        __syncthreads();
        int wb = 0;
#pragma unroll
        for (int i = 0; i < 4; ++i) if (i < w) wb += wsum[i];
        int excl = wb + incl - sv;
        cur[t] = excl;
        if ((t & 63) == 0) off2[b * NSLAB + (t >> 6)] = base + excl;   // slab segment base
        if (t < BWID) {
            int node = (b << BW_LOG) + t;
            if (node < n_nodes)
                deg[node] = hist[t] + hist[BWID + t] + hist[2 * BWID + t] + hist[3 * BWID + t];
        }
    }
    __syncthreads();
    for (int i = t; i < n_b && i < CAP; i += 256) {
        u32 v = in_s[i];
        int key = (int)((v & 0xffffu) / (u32)sw) * BWID + (int)(v >> 16);
        int p = atomicAdd(&cur[key], 1);
        if (p < CAP) out_s[p] = v;
    }
    __syncthreads();
    for (int i = t; i < n_b && i < CAP; i += 256) ebuf[base + i] = out_s[i];
}

// ---------- cooperative slab-phased mean aggregation ----------
// One block per bucket (64 nodes), 512 threads = 16 half-waves, LDS f32 planes
// acc[4][64][33] (bank = (dl+lane)%32: conflict-free). Slab loop outermost: all 782
// blocks co-resident (4/CU) sweep slab 0..3 in loose lockstep -> per-XCD L2-resident
// phases (R10 measured FETCH 209->71MB). Per (bucket,slab) segment ~512 contiguous
// edges; half-wave takes 4 edges/iter (4 rows in flight), LDS-atomic accumulate.

__global__ __launch_bounds__(512)
void aggregate_coop_kernel(const u16* __restrict__ xb, const int* __restrict__ off2,
                           const int* __restrict__ deg, const u32* __restrict__ eidx,
                           u16* __restrict__ meanb, int n_nodes) {
    __shared__ float acc[4][BWID][33];
    int t = threadIdx.x;
    int hw = t >> 5;          // half-wave 0..15
    int lane = t & 31;
    int b = blockIdx.x;

    for (int i = t; i < 4 * BWID * 33; i += 512) ((float*)acc)[i] = 0.f;
    __syncthreads();

    for (int s = 0; s < NSLAB; ++s) {
        int lo = off2[b * NSLAB + s];
        int hi = off2[b * NSLAB + s + 1];
        for (int e = lo + hw * 4; e < hi; e += 64) {
            if (e + 4 <= hi) {
                u32 r0 = eidx[e + 0], r1 = eidx[e + 1], r2 = eidx[e + 2], r3 = eidx[e + 3];
                ushort4 v0 = *(const ushort4*)&xb[(size_t)(r0 & 0xffffu) * D + lane * 4];
                ushort4 v1 = *(const ushort4*)&xb[(size_t)(r1 & 0xffffu) * D + lane * 4];
                ushort4 v2 = *(const ushort4*)&xb[(size_t)(r2 & 0xffffu) * D + lane * 4];
                ushort4 v3 = *(const ushort4*)&xb[(size_t)(r3 & 0xffffu) * D + lane * 4];
                int d0 = r0 >> 16, d1 = r1 >> 16, d2 = r2 >> 16, d3 = r3 >> 16;
                atomicAdd(&acc[0][d0][lane], bf2f(v0.x));
                atomicAdd(&acc[1][d0][lane], bf2f(v0.y));
                atomicAdd(&acc[2][d0][lane], bf2f(v0.z));
                atomicAdd(&acc[3][d0][lane], bf2f(v0.w));
                atomicAdd(&acc[0][d1][lane], bf2f(v1.x));
                atomicAdd(&acc[1][d1][lane], bf2f(v1.y));
                atomicAdd(&acc[2][d1][lane], bf2f(v1.z));
                atomicAdd(&acc[3][d1][lane], bf2f(v1.w));
                atomicAdd(&acc[0][d2][lane], bf2f(v2.x));
                atomicAdd(&acc[1][d2][lane], bf2f(v2.y));
                atomicAdd(&acc[2][d2][lane], bf2f(v2.z));
                atomicAdd(&acc[3][d2][lane], bf2f(v2.w));
                atomicAdd(&acc[0][d3][lane], bf2f(v3.x));
                atomicAdd(&acc[1][d3][lane], bf2f(v3.y));
                atomicAdd(&acc[2][d3][lane], bf2f(v3.z));
                atomicAdd(&acc[3][d3][lane], bf2f(v3.w));
            } else {
                for (int k = e; k < hi; ++k) {
                    u32 r = eidx[k];
                    ushort4 v = *(const ushort4*)&xb[(size_t)(r & 0xffffu) * D + lane * 4];
                    int d = r >> 16;
                    atomicAdd(&acc[0][d][lane], bf2f(v.x));
                    atomicAdd(&acc[1][d][lane], bf2f(v.y));
                    atomicAdd(&acc[2][d][lane], bf2f(v.z));
                    atomicAdd(&acc[3][d][lane], bf2f(v.w));
                }
            }
        }
    }
    __syncthreads();

    for (int dl = hw; dl < BWID; dl += 16) {
        int node = (b << BW_LOG) + dl;
        if (node >= n_nodes) continue;
        int dg = deg[node];
        float inv = 1.f / (float)(dg > 0 ? dg : 1);
        ushort4 o;
        o.x = f2bf(acc[0][dl][lane] * inv);
        o.y = f2bf(acc[1][dl][lane] * inv);
        o.z = f2bf(acc[2][dl][lane] * inv);
        o.w = f2bf(acc[3][dl][lane] * inv);
        *(ushort4*)&meanb[(size_t)node * D + lane * 4] = o;
    }
}

// ---------- linear via MFMA with LDS-staged W ----------
// out = relu([mean||self] @ Wcat^T + b). Block = 128 rows (8 waves x 16-row tiles).
// mfma_f32_16x16x32_bf16: A row=l&15, k=(l>>4)*8+j ; C/D col=l&15, row=(l>>4)*4+reg.

template<bool OUT_BF16>
__global__ __launch_bounds__(512)
void linear_mfma_kernel(const u16* __restrict__ Amean, const u16* __restrict__ Aself,
                        const u16* __restrict__ Wc, const float* __restrict__ bias,
                        void* __restrict__ outp, int N) {
    __shared__ u16 ws[128][136];   // 34816 B

    int t = threadIdx.x;
    int l = t & 63;
    int wv = t >> 6;               // 0..7
    int m0 = blockIdx.x * 128 + wv * 16;
    int lr = l & 15;
    int kg = (l >> 4) * 8;
    int rowA = m0 + lr;
    int rc = rowA < N ? rowA : N - 1;
    const u16* r1 = Amean + (size_t)rc * D;
    const u16* r2 = Aself + (size_t)rc * D;

    bf16x8 a[8];
#pragma unroll
    for (int kt = 0; kt < 4; ++kt) {
        a[kt]     = *(const bf16x8*)(r1 + kt * 32 + kg);   // k 0..127  (mean)
        a[kt + 4] = *(const bf16x8*)(r2 + kt * 32 + kg);   // k 128..255 (self)
    }

    f32x4 acc[8];
#pragma unroll
    for (int nt = 0; nt < 8; ++nt) acc[nt] = (f32x4){0.f, 0.f, 0.f, 0.f};

    for (int half = 0; half < 2; ++half) {
        if (half) __syncthreads();
        for (int i = t; i < 2048; i += 512) {
            int n = i >> 4, kq = i & 15;
            *(u16x8*)&ws[n][kq * 8] = *(const u16x8*)&Wc[(size_t)n * 256 + half * 128 + kq * 8];
        }
        __syncthreads();

#pragma unroll
        for (int nt = 0; nt < 8; ++nt) {
            bf16x8 b0 = *(const bf16x8*)&ws[nt * 16 + lr][0 * 32 + kg];
            bf16x8 b1 = *(const bf16x8*)&ws[nt * 16 + lr][1 * 32 + kg];
            bf16x8 b2 = *(const bf16x8*)&ws[nt * 16 + lr][2 * 32 + kg];
            bf16x8 b3 = *(const bf16x8*)&ws[nt * 16 + lr][3 * 32 + kg];
            acc[nt] = __builtin_amdgcn_mfma_f32_16x16x32_bf16(a[half * 4 + 0], b0, acc[nt], 0, 0, 0);
            acc[nt] = __builtin_amdgcn_mfma_f32_16x16x32_bf16(a[half * 4 + 1], b1, acc[nt], 0, 0, 0);
            acc[nt] = __builtin_amdgcn_mfma_f32_16x16x32_bf16(a[half * 4 + 2], b2, acc[nt], 0, 0, 0);
            acc[nt] = __builtin_amdgcn_mfma_f32_16x16x32_bf16(a[half * 4 + 3], b3, acc[nt], 0, 0, 0);
        }
    }

#pragma unroll
    for (int nt = 0; nt < 8; ++nt) {
        int col = nt * 16 + lr;
        float bb = bias[col];
#pragma unroll
        for (int j = 0; j < 4; ++j) {
            int r = m0 + (l >> 4) * 4 + j;
            if (r < N) {
                float v = fmaxf(acc[nt][j] + bb, 0.f);
                if (OUT_BF16) ((u16*)outp)[(size_t)r * D + col] = f2bf(v);
                else          ((float*)outp)[(size_t)r * D + col] = v;
            }
        }
    }
}

extern "C" void kernel_launch(void* const* d_in, const int* in_sizes, int n_in,
                              void* d_out, int out_size, void* d_ws, size_t ws_size,
                              hipStream_t stream) {
    const float* x   = (const float*)d_in[0];
    const int*   ei  = (const int*)d_in[1];
    const float* W1l = (const float*)d_in[2];
    const float* W1r = (const float*)d_in[3];
    const float* b1  = (const float*)d_in[4];
    const float* W2l = (const float*)d_in[5];
    const float* W2r = (const float*)d_in[6];
    const float* b2  = (const float*)d_in[7];
    float* out = (float*)d_out;

    const int N = in_sizes[0] / D;
    const int E = in_sizes[1] / 2;
    const int* src = ei;
    const int* dst = ei + E;
    const int NB = (N + BWID - 1) >> BW_LOG;       // 782 for N=50000 (<= NB_MAX)
    const int NBLK = (E + CHUNK - 1) / CHUNK;      // 391 for E=1.6M
    const int SW = (N + NSLAB - 1) / NSLAB;        // 12500: slab width
    const int N4 = N * D / 4;
    const int XBLK = (N4 + 255) / 256;             // 6250

    // workspace layout, 64B-aligned blocks
    char* wp_ = (char*)d_ws;
    auto alloc = [&](size_t bytes) { char* p = wp_; wp_ += (bytes + 63) & ~(size_t)63; return p; };
    int* off2_p  = (int*)alloc((size_t)(NB * NSLAB + 1) * 4);
    int* deg_p   = (int*)alloc((size_t)N * 4);
    int* bbase_p = (int*)alloc((size_t)(NB + 1) * 4);
    int* btot_p  = (int*)alloc((size_t)NB * 4);
    int* gh_p    = (int*)alloc((size_t)NB * NBLK * 4);
    u32* ebuf_p  = (u32*)alloc((size_t)E * 4);
    u16* xb      = (u16*)alloc((size_t)N * D * 2);
    u16* meanb   = (u16*)alloc((size_t)N * D * 2);
    u16* h1b     = (u16*)alloc((size_t)N * D * 2);
    u16* wc1     = (u16*)alloc((size_t)128 * 256 * 2);
    u16* wc2     = (u16*)alloc((size_t)128 * 256 * 2);

    // fused prep: cvt_x + cvt_w + part_hist
    prep_kernel<<<XBLK + 256 + NBLK, 256, 0, stream>>>(
        x, xb, N4, W1l, W1r, W2l, W2r, wc1, wc2, dst, gh_p, E, NB, NBLK, XBLK);

    // CSR build (slab-major within buckets)
    part_scan1_kernel<<<NB, 64, 0, stream>>>(gh_p, btot_p, NBLK);
    part_scan2_kernel<<<1, 1024, 0, stream>>>(btot_p, bbase_p, NB, off2_p + (size_t)NB * NSLAB);
    part_scatter_kernel<<<NBLK, 256, 0, stream>>>(src, dst, gh_p, bbase_p, ebuf_p, E, NB, NBLK);
    bucket_sort_kernel<<<NB, 256, 0, stream>>>(ebuf_p, bbase_p, off2_p, deg_p, N, SW);

    // layer 1
    aggregate_coop_kernel<<<NB, 512, 0, stream>>>(xb, off2_p, deg_p, ebuf_p, meanb, N);
    linear_mfma_kernel<true><<<(N + 127) / 128, 512, 0, stream>>>(meanb, xb, wc1, b1, h1b, N);

    // layer 2
    aggregate_coop_kernel<<<NB, 512, 0, stream>>>(h1b, off2_p, deg_p, ebuf_p, meanb, N);
    linear_mfma_kernel<false><<<(N + 127) / 128, 512, 0, stream>>>(meanb, h1b, wc2, b2, out, N);
}

// Round 13
// 224.155 us; speedup vs baseline: 12.3999x; 12.3999x over previous
//
#include <hip/hip_runtime.h>

#define D 128
#define DH 64             // half feature dim (split tables for L2 residency)
#define BW_LOG 6          // 64 nodes per bucket
#define BWID 64
#define CAP 4096          // max edges per bucket in LDS (mean ~2048, max ~2350)
#define CHUNK 4096        // edges per partition block (391 blocks -> occupancy)
#define NB_MAX 1024       // supports N <= 65536 (also required by 16-bit src packing)

typedef unsigned short u16;
typedef unsigned int u32;
typedef __attribute__((ext_vector_type(8))) short bf16x8;      // 8 bf16 (4 VGPRs)
typedef __attribute__((ext_vector_type(8))) unsigned short u16x8;
typedef __attribute__((ext_vector_type(4))) float f32x4;

__device__ __forceinline__ float bf2f(u16 h) { return __uint_as_float(((u32)h) << 16); }
__device__ __forceinline__ u16 f2bf(float f) {
    u32 u = __float_as_uint(f);
    u32 r = (u + 0x7fffu + ((u >> 16) & 1u)) >> 16;   // RNE
    return (u16)r;
}

// ---------- fused prep: cvt_x (split halves) + cvt_w + part_hist ----------

__global__ __launch_bounds__(256)
void prep_kernel(const float* __restrict__ x, u16* __restrict__ xb0, u16* __restrict__ xb1,
                 int n4,
                 const float* __restrict__ W1l, const float* __restrict__ W1r,
                 const float* __restrict__ W2l, const float* __restrict__ W2r,
                 u16* __restrict__ wc1, u16* __restrict__ wc2,
                 const int* __restrict__ dst, int* __restrict__ gh,
                 int E, int nb, int nblk, int xblk) {
    __shared__ int h[NB_MAX];
    int b = blockIdx.x;
    int t = threadIdx.x;
    if (b < xblk) {
        int i = b * 256 + t;
        if (i < n4) {
            float4 v = ((const float4*)x)[i];
            ushort4 o;
            o.x = f2bf(v.x); o.y = f2bf(v.y); o.z = f2bf(v.z); o.w = f2bf(v.w);
            int n = i >> 5;             // node (32 float4 per node)
            int d0 = (i & 31) * 4;      // dim base
            u16* dstp = (d0 < DH) ? (xb0 + (size_t)n * DH + d0)
                                  : (xb1 + (size_t)n * DH + d0 - DH);
            *(ushort4*)dstp = o;
        }
        return;
    }
    if (b < xblk + 256) {
        int wb = b - xblk;
        int n = wb & 127;
        const float* Wl = (wb < 128) ? W1l : W2l;
        const float* Wr = (wb < 128) ? W1r : W2r;
        u16* wcat = (wb < 128) ? wc1 : wc2;
        float v = (t < 128) ? Wl[n * 128 + t] : Wr[n * 128 + t - 128];
        wcat[n * 256 + t] = f2bf(v);
        return;
    }
    int hb = b - xblk - 256;
    for (int i = t; i < nb; i += 256) h[i] = 0;
    __syncthreads();
    int lo = hb * CHUNK, hi = min(lo + CHUNK, E);
    for (int i = lo + t; i < hi; i += 256) atomicAdd(&h[dst[i] >> BW_LOG], 1);
    __syncthreads();
    for (int i = t; i < nb; i += 256) gh[(size_t)i * nblk + hb] = h[i];
}

// ---------- CSR build (R11 chain, unchanged) ----------

__global__ __launch_bounds__(64)
void part_scan1_kernel(int* __restrict__ gh, int* __restrict__ btot, int nblk) {
    int k = blockIdx.x;
    int t = threadIdx.x;
    int* row = gh + (size_t)k * nblk;
    int chunk = (nblk + 63) >> 6;
    int lo = t * chunk, hi = min(lo + chunk, nblk);
    int s = 0;
    for (int i = lo; i < hi; ++i) s += row[i];
    int incl = s;
#pragma unroll
    for (int d2 = 1; d2 < 64; d2 <<= 1) { int u = __shfl_up(incl, d2, 64); if (t >= d2) incl += u; }
    int excl = incl - s;
    for (int i = lo; i < hi; ++i) { int c = row[i]; row[i] = excl; excl += c; }
    if (t == 63) btot[k] = incl;
}

__global__ __launch_bounds__(1024)
void part_scan2_kernel(const int* __restrict__ btot, int* __restrict__ bbase,
                       int nb, int* __restrict__ offN) {
    __shared__ int ws[16];
    int t = threadIdx.x, lane = t & 63, wid = t >> 6;
    int v = (t < nb) ? btot[t] : 0;
    int incl = v;
#pragma unroll
    for (int d2 = 1; d2 < 64; d2 <<= 1) { int u = __shfl_up(incl, d2, 64); if (lane >= d2) incl += u; }
    if (lane == 63) ws[wid] = incl;
    __syncthreads();
    if (wid == 0) {
        int w = (lane < 16) ? ws[lane] : 0;
#pragma unroll
        for (int d2 = 1; d2 < 16; d2 <<= 1) { int u = __shfl_up(w, d2, 64); if (lane >= d2) w += u; }
        if (lane < 16) ws[lane] = w;
    }
    __syncthreads();
    int base = wid ? ws[wid - 1] : 0;
    int excl = base + incl - v;
    if (t < nb) bbase[t] = excl;
    if (t == nb - 1) { bbase[nb] = excl + v; *offN = excl + v; }
}

// record = (dst_local << 16) | src   (src < 65536)
__global__ __launch_bounds__(256)
void part_scatter_kernel(const int* __restrict__ src, const int* __restrict__ dst,
                         const int* __restrict__ gh, const int* __restrict__ bbase,
                         u32* __restrict__ ebuf, int E, int nb, int nblk) {
    __shared__ int cur[NB_MAX];
    int b = blockIdx.x;
    for (int i = threadIdx.x; i < nb; i += 256)
        cur[i] = bbase[i] + gh[(size_t)i * nblk + b];
    __syncthreads();
    int lo = b * CHUNK, hi = min(lo + CHUNK, E);
    for (int i = lo + threadIdx.x; i < hi; i += 256) {
        int d = dst[i];
        int p = atomicAdd(&cur[d >> BW_LOG], 1);
        ebuf[p] = ((u32)(d & (BWID - 1)) << 16) | (u32)src[i];
    }
}

__global__ __launch_bounds__(256)
void bucket_sort_kernel(u32* __restrict__ ebuf, const int* __restrict__ bbase,
                        int* __restrict__ off, int n_nodes) {
    __shared__ u32 in_s[CAP];
    __shared__ u16 out_s[CAP];
    __shared__ int hist[BWID], cur[BWID];
    int b = blockIdx.x;
    int base = bbase[b];
    int n_b = bbase[b + 1] - base;
    int t = threadIdx.x;
    if (t < BWID) hist[t] = 0;
    for (int i = t; i < n_b && i < CAP; i += 256) in_s[i] = ebuf[base + i];
    __syncthreads();
    for (int i = t; i < n_b && i < CAP; i += 256) atomicAdd(&hist[in_s[i] >> 16], 1);
    __syncthreads();
    if (t < BWID) {
        int s = hist[t];
        int incl = s;
#pragma unroll
        for (int d2 = 1; d2 < 64; d2 <<= 1) { int u = __shfl_up(incl, d2, 64); if (t >= d2) incl += u; }
        int excl = incl - s;
        cur[t] = excl;
        int node = (b << BW_LOG) + t;
        if (node < n_nodes) off[node] = base + excl;
    }
    __syncthreads();
    for (int i = t; i < n_b && i < CAP; i += 256) {
        u32 v = in_s[i];
        int p = atomicAdd(&cur[v >> 16], 1);
        if (p < CAP) out_s[p] = (u16)(v & 0xffffu);
    }
    __syncthreads();
    for (int i = t; i < n_b && i < CAP; i += 256) ebuf[base + i] = (u32)out_s[i];
}

// ---------- half-table mean aggregation ----------
// 16 lanes per node (ushort4 covers DH=64), 16 nodes/block, unroll x8.
// Per-wave in-flight = 32 half-rows x 128B = 4KB (the R5-measured sweet spot);
// gather table = 6.4MB -> better per-XCD L2 residency than 12.8MB full rows.

__global__ __launch_bounds__(256)
void aggregate_half_kernel(const u16* __restrict__ xh, const int* __restrict__ off,
                           const u32* __restrict__ eidx, u16* __restrict__ mh,
                           int n_nodes) {
    int node = blockIdx.x * 16 + (threadIdx.x >> 4);
    int lane = threadIdx.x & 15;
    if (node >= n_nodes) return;
    int beg = off[node], end = off[node + 1];
    int c = lane * 4;

    float ax = 0.f, ay = 0.f, az = 0.f, aw = 0.f;
    int e = beg;
    for (; e + 8 <= end; e += 8) {
        ushort4 v0 = *(const ushort4*)&xh[(size_t)eidx[e + 0] * DH + c];
        ushort4 v1 = *(const ushort4*)&xh[(size_t)eidx[e + 1] * DH + c];
        ushort4 v2 = *(const ushort4*)&xh[(size_t)eidx[e + 2] * DH + c];
        ushort4 v3 = *(const ushort4*)&xh[(size_t)eidx[e + 3] * DH + c];
        ushort4 v4 = *(const ushort4*)&xh[(size_t)eidx[e + 4] * DH + c];
        ushort4 v5 = *(const ushort4*)&xh[(size_t)eidx[e + 5] * DH + c];
        ushort4 v6 = *(const ushort4*)&xh[(size_t)eidx[e + 6] * DH + c];
        ushort4 v7 = *(const ushort4*)&xh[(size_t)eidx[e + 7] * DH + c];
        ax += bf2f(v0.x) + bf2f(v1.x) + bf2f(v2.x) + bf2f(v3.x)
            + bf2f(v4.x) + bf2f(v5.x) + bf2f(v6.x) + bf2f(v7.x);
        ay += bf2f(v0.y) + bf2f(v1.y) + bf2f(v2.y) + bf2f(v3.y)
            + bf2f(v4.y) + bf2f(v5.y) + bf2f(v6.y) + bf2f(v7.y);
        az += bf2f(v0.z) + bf2f(v1.z) + bf2f(v2.z) + bf2f(v3.z)
            + bf2f(v4.z) + bf2f(v5.z) + bf2f(v6.z) + bf2f(v7.z);
        aw += bf2f(v0.w) + bf2f(v1.w) + bf2f(v2.w) + bf2f(v3.w)
            + bf2f(v4.w) + bf2f(v5.w) + bf2f(v6.w) + bf2f(v7.w);
    }
    for (; e < end; ++e) {
        ushort4 v = *(const ushort4*)&xh[(size_t)eidx[e] * DH + c];
        ax += bf2f(v.x); ay += bf2f(v.y); az += bf2f(v.z); aw += bf2f(v.w);
    }

    int deg = end - beg;
    float inv = 1.f / (float)(deg > 0 ? deg : 1);
    ushort4 o;
    o.x = f2bf(ax * inv); o.y = f2bf(ay * inv); o.z = f2bf(az * inv); o.w = f2bf(aw * inv);
    *(ushort4*)&mh[(size_t)node * DH + c] = o;
}

// ---------- linear via MFMA with LDS-staged W (split-half A operands) ----------
// out = relu([mean||self] @ Wcat^T + b). Block = 128 rows (8 waves x 16-row tiles).
// mfma_f32_16x16x32_bf16: A row=l&15, k=(l>>4)*8+j ; C/D col=l&15, row=(l>>4)*4+reg.

template<bool OUT_BF16>
__global__ __launch_bounds__(512)
void linear_mfma_kernel(const u16* __restrict__ Am0, const u16* __restrict__ Am1,
                        const u16* __restrict__ As0, const u16* __restrict__ As1,
                        const u16* __restrict__ Wc, const float* __restrict__ bias,
                        void* __restrict__ o0, void* __restrict__ o1, int N) {
    __shared__ u16 ws[128][136];   // 34816 B

    int t = threadIdx.x;
    int l = t & 63;
    int wv = t >> 6;               // 0..7
    int m0 = blockIdx.x * 128 + wv * 16;
    int lr = l & 15;
    int kg = (l >> 4) * 8;
    int rowA = m0 + lr;
    int rc = rowA < N ? rowA : N - 1;

    bf16x8 a[8];
    a[0] = *(const bf16x8*)(Am0 + (size_t)rc * DH + kg);        // k 0..63   (mean lo)
    a[1] = *(const bf16x8*)(Am0 + (size_t)rc * DH + 32 + kg);
    a[2] = *(const bf16x8*)(Am1 + (size_t)rc * DH + kg);        // k 64..127 (mean hi)
    a[3] = *(const bf16x8*)(Am1 + (size_t)rc * DH + 32 + kg);
    a[4] = *(const bf16x8*)(As0 + (size_t)rc * DH + kg);        // k 128..191 (self lo)
    a[5] = *(const bf16x8*)(As0 + (size_t)rc * DH + 32 + kg);
    a[6] = *(const bf16x8*)(As1 + (size_t)rc * DH + kg);        // k 192..255 (self hi)
    a[7] = *(const bf16x8*)(As1 + (size_t)rc * DH + 32 + kg);

    f32x4 acc[8];
#pragma unroll
    for (int nt = 0; nt < 8; ++nt) acc[nt] = (f32x4){0.f, 0.f, 0.f, 0.f};

    for (int half = 0; half < 2; ++half) {
        if (half) __syncthreads();
        for (int i = t; i < 2048; i += 512) {
            int n = i >> 4, kq = i & 15;
            *(u16x8*)&ws[n][kq * 8] = *(const u16x8*)&Wc[(size_t)n * 256 + half * 128 + kq * 8];
        }
        __syncthreads();

#pragma unroll
        for (int nt = 0; nt < 8; ++nt) {
            bf16x8 b0 = *(const bf16x8*)&ws[nt * 16 + lr][0 * 32 + kg];
            bf16x8 b1 = *(const bf16x8*)&ws[nt * 16 + lr][1 * 32 + kg];
            bf16x8 b2 = *(const bf16x8*)&ws[nt * 16 + lr][2 * 32 + kg];
            bf16x8 b3 = *(const bf16x8*)&ws[nt * 16 + lr][3 * 32 + kg];
            acc[nt] = __builtin_amdgcn_mfma_f32_16x16x32_bf16(a[half * 4 + 0], b0, acc[nt], 0, 0, 0);
            acc[nt] = __builtin_amdgcn_mfma_f32_16x16x32_bf16(a[half * 4 + 1], b1, acc[nt], 0, 0, 0);
            acc[nt] = __builtin_amdgcn_mfma_f32_16x16x32_bf16(a[half * 4 + 2], b2, acc[nt], 0, 0, 0);
            acc[nt] = __builtin_amdgcn_mfma_f32_16x16x32_bf16(a[half * 4 + 3], b3, acc[nt], 0, 0, 0);
        }
    }

#pragma unroll
    for (int nt = 0; nt < 8; ++nt) {
        int col = nt * 16 + lr;
        float bb = bias[col];
#pragma unroll
        for (int j = 0; j < 4; ++j) {
            int r = m0 + (l >> 4) * 4 + j;
            if (r < N) {
                float v = fmaxf(acc[nt][j] + bb, 0.f);
                if (OUT_BF16) {
                    // split-half bf16 output (feeds next layer's gather/linear)
                    if (col < DH) ((u16*)o0)[(size_t)r * DH + col] = f2bf(v);
                    else          ((u16*)o1)[(size_t)r * DH + col - DH] = f2bf(v);
                } else {
                    ((float*)o0)[(size_t)r * D + col] = v;
                }
            }
        }
    }
}

extern "C" void kernel_launch(void* const* d_in, const int* in_sizes, int n_in,
                              void* d_out, int out_size, void* d_ws, size_t ws_size,
                              hipStream_t stream) {
    const float* x   = (const float*)d_in[0];
    const int*   ei  = (const int*)d_in[1];
    const float* W1l = (const float*)d_in[2];
    const float* W1r = (const float*)d_in[3];
    const float* b1  = (const float*)d_in[4];
    const float* W2l = (const float*)d_in[5];
    const float* W2r = (const float*)d_in[6];
    const float* b2  = (const float*)d_in[7];
    float* out = (float*)d_out;

    const int N = in_sizes[0] / D;
    const int E = in_sizes[1] / 2;
    const int* src = ei;
    const int* dst = ei + E;
    const int NB = (N + BWID - 1) >> BW_LOG;       // 782 for N=50000 (<= NB_MAX)
    const int NBLK = (E + CHUNK - 1) / CHUNK;      // 391 for E=1.6M
    const int N4 = N * D / 4;
    const int XBLK = (N4 + 255) / 256;             // 6250

    // workspace layout, 64B-aligned blocks
    char* wp_ = (char*)d_ws;
    auto alloc = [&](size_t bytes) { char* p = wp_; wp_ += (bytes + 63) & ~(size_t)63; return p; };
    int* off_p   = (int*)alloc((size_t)(N + 1) * 4);
    int* bbase_p = (int*)alloc((size_t)(NB + 1) * 4);
    int* btot_p  = (int*)alloc((size_t)NB * 4);
    int* gh_p    = (int*)alloc((size_t)NB * NBLK * 4);
    u32* ebuf_p  = (u32*)alloc((size_t)E * 4);
    u16* xb0     = (u16*)alloc((size_t)N * DH * 2);
    u16* xb1     = (u16*)alloc((size_t)N * DH * 2);
    u16* mean0   = (u16*)alloc((size_t)N * DH * 2);
    u16* mean1   = (u16*)alloc((size_t)N * DH * 2);
    u16* h1b0    = (u16*)alloc((size_t)N * DH * 2);
    u16* h1b1    = (u16*)alloc((size_t)N * DH * 2);
    u16* wc1     = (u16*)alloc((size_t)128 * 256 * 2);
    u16* wc2     = (u16*)alloc((size_t)128 * 256 * 2);

    // fused prep: cvt_x (split) + cvt_w + part_hist
    prep_kernel<<<XBLK + 256 + NBLK, 256, 0, stream>>>(
        x, xb0, xb1, N4, W1l, W1r, W2l, W2r, wc1, wc2, dst, gh_p, E, NB, NBLK, XBLK);

    // CSR build
    part_scan1_kernel<<<NB, 64, 0, stream>>>(gh_p, btot_p, NBLK);
    part_scan2_kernel<<<1, 1024, 0, stream>>>(btot_p, bbase_p, NB, off_p + N);
    part_scatter_kernel<<<NBLK, 256, 0, stream>>>(src, dst, gh_p, bbase_p, ebuf_p, E, NB, NBLK);
    bucket_sort_kernel<<<NB, 256, 0, stream>>>(ebuf_p, bbase_p, off_p, N);

    const int AGRID = (N + 15) / 16;

    // layer 1: two half-table gathers (6.4MB working set each), then MFMA linear
    aggregate_half_kernel<<<AGRID, 256, 0, stream>>>(xb0, off_p, ebuf_p, mean0, N);
    aggregate_half_kernel<<<AGRID, 256, 0, stream>>>(xb1, off_p, ebuf_p, mean1, N);
    linear_mfma_kernel<true><<<(N + 127) / 128, 512, 0, stream>>>(
        mean0, mean1, xb0, xb1, wc1, b1, h1b0, h1b1, N);

    // layer 2
    aggregate_half_kernel<<<AGRID, 256, 0, stream>>>(h1b0, off_p, ebuf_p, mean0, N);
    aggregate_half_kernel<<<AGRID, 256, 0, stream>>>(h1b1, off_p, ebuf_p, mean1, N);
    linear_mfma_kernel<false><<<(N + 127) / 128, 512, 0, stream>>>(
        mean0, mean1, h1b0, h1b1, wc2, b2, out, nullptr, N);
}

// Round 14
// 184.210 us; speedup vs baseline: 15.0888x; 1.2168x over previous
//
#include <hip/hip_runtime.h>

#define D 128
#define BW_LOG 6          // 64 nodes per bucket
#define BWID 64
#define CAP 4096          // max edges per bucket in LDS (mean ~2048, max ~2350)
#define CHUNK 4096        // edges per partition block (391 blocks -> occupancy)
#define NB_MAX 1024       // supports N <= 65536 (also required by 16-bit src packing)

typedef unsigned short u16;
typedef unsigned int u32;
typedef __attribute__((ext_vector_type(8))) short bf16x8;      // 8 bf16 (4 VGPRs)
typedef __attribute__((ext_vector_type(8))) unsigned short u16x8;
typedef __attribute__((ext_vector_type(4))) float f32x4;

__device__ __forceinline__ float bf2f(u16 h) { return __uint_as_float(((u32)h) << 16); }
__device__ __forceinline__ u16 f2bf(float f) {
    u32 u = __float_as_uint(f);
    u32 r = (u + 0x7fffu + ((u >> 16) & 1u)) >> 16;   // RNE
    return (u16)r;
}

// ---------- fused prep: cvt_x + cvt_w + part_hist in one block-partitioned launch ----------

__global__ __launch_bounds__(256)
void prep_kernel(const float* __restrict__ x, u16* __restrict__ xb, int n4,
                 const float* __restrict__ W1l, const float* __restrict__ W1r,
                 const float* __restrict__ W2l, const float* __restrict__ W2r,
                 u16* __restrict__ wc1, u16* __restrict__ wc2,
                 const int* __restrict__ dst, int* __restrict__ gh,
                 int E, int nb, int nblk, int xblk) {
    __shared__ int h[NB_MAX];
    int b = blockIdx.x;
    int t = threadIdx.x;
    if (b < xblk) {
        int i = b * 256 + t;
        if (i < n4) {
            float4 v = ((const float4*)x)[i];
            ushort4 o;
            o.x = f2bf(v.x); o.y = f2bf(v.y); o.z = f2bf(v.z); o.w = f2bf(v.w);
            ((ushort4*)xb)[i] = o;
        }
        return;
    }
    if (b < xblk + 256) {
        int wb = b - xblk;
        int n = wb & 127;
        const float* Wl = (wb < 128) ? W1l : W2l;
        const float* Wr = (wb < 128) ? W1r : W2r;
        u16* wcat = (wb < 128) ? wc1 : wc2;
        float v = (t < 128) ? Wl[n * 128 + t] : Wr[n * 128 + t - 128];
        wcat[n * 256 + t] = f2bf(v);
        return;
    }
    int hb = b - xblk - 256;
    for (int i = t; i < nb; i += 256) h[i] = 0;
    __syncthreads();
    int lo = hb * CHUNK, hi = min(lo + CHUNK, E);
    for (int i = lo + t; i < hi; i += 256) atomicAdd(&h[dst[i] >> BW_LOG], 1);
    __syncthreads();
    for (int i = t; i < nb; i += 256) gh[(size_t)i * nblk + hb] = h[i];
}

// ---------- CSR build ----------

__global__ __launch_bounds__(64)
void part_scan1_kernel(int* __restrict__ gh, int* __restrict__ btot, int nblk) {
    int k = blockIdx.x;
    int t = threadIdx.x;
    int* row = gh + (size_t)k * nblk;
    int chunk = (nblk + 63) >> 6;
    int lo = t * chunk, hi = min(lo + chunk, nblk);
    int s = 0;
    for (int i = lo; i < hi; ++i) s += row[i];
    int incl = s;
#pragma unroll
    for (int d2 = 1; d2 < 64; d2 <<= 1) { int u = __shfl_up(incl, d2, 64); if (t >= d2) incl += u; }
    int excl = incl - s;
    for (int i = lo; i < hi; ++i) { int c = row[i]; row[i] = excl; excl += c; }
    if (t == 63) btot[k] = incl;
}

__global__ __launch_bounds__(1024)
void part_scan2_kernel(const int* __restrict__ btot, int* __restrict__ bbase,
                       int nb, int* __restrict__ offN) {
    __shared__ int ws[16];
    int t = threadIdx.x, lane = t & 63, wid = t >> 6;
    int v = (t < nb) ? btot[t] : 0;
    int incl = v;
#pragma unroll
    for (int d2 = 1; d2 < 64; d2 <<= 1) { int u = __shfl_up(incl, d2, 64); if (lane >= d2) incl += u; }
    if (lane == 63) ws[wid] = incl;
    __syncthreads();
    if (wid == 0) {
        int w = (lane < 16) ? ws[lane] : 0;
#pragma unroll
        for (int d2 = 1; d2 < 16; d2 <<= 1) { int u = __shfl_up(w, d2, 64); if (lane >= d2) w += u; }
        if (lane < 16) ws[lane] = w;
    }
    __syncthreads();
    int base = wid ? ws[wid - 1] : 0;
    int excl = base + incl - v;
    if (t < nb) bbase[t] = excl;
    if (t == nb - 1) { bbase[nb] = excl + v; *offN = excl + v; }
}

// record = (dst_local << 16) | src   (src < 65536)
__global__ __launch_bounds__(256)
void part_scatter_kernel(const int* __restrict__ src, const int* __restrict__ dst,
                         const int* __restrict__ gh, const int* __restrict__ bbase,
                         u32* __restrict__ ebuf, int E, int nb, int nblk) {
    __shared__ int cur[NB_MAX];
    int b = blockIdx.x;
    for (int i = threadIdx.x; i < nb; i += 256)
        cur[i] = bbase[i] + gh[(size_t)i * nblk + b];
    __syncthreads();
    int lo = b * CHUNK, hi = min(lo + CHUNK, E);
    for (int i = lo + threadIdx.x; i < hi; i += 256) {
        int d = dst[i];
        int p = atomicAdd(&cur[d >> BW_LOG], 1);
        ebuf[p] = ((u32)(d & (BWID - 1)) << 16) | (u32)src[i];
    }
}

__global__ __launch_bounds__(256)
void bucket_sort_kernel(u32* __restrict__ ebuf, const int* __restrict__ bbase,
                        int* __restrict__ off, int n_nodes) {
    __shared__ u32 in_s[CAP];
    __shared__ u16 out_s[CAP];
    __shared__ int hist[BWID], cur[BWID];
    int b = blockIdx.x;
    int base = bbase[b];
    int n_b = bbase[b + 1] - base;
    int t = threadIdx.x;
    if (t < BWID) hist[t] = 0;
    for (int i = t; i < n_b && i < CAP; i += 256) in_s[i] = ebuf[base + i];
    __syncthreads();
    for (int i = t; i < n_b && i < CAP; i += 256) atomicAdd(&hist[in_s[i] >> 16], 1);
    __syncthreads();
    if (t < BWID) {
        int s = hist[t];
        int incl = s;
#pragma unroll
        for (int d2 = 1; d2 < 64; d2 <<= 1) { int u = __shfl_up(incl, d2, 64); if (t >= d2) incl += u; }
        int excl = incl - s;
        cur[t] = excl;
        int node = (b << BW_LOG) + t;
        if (node < n_nodes) off[node] = base + excl;
    }
    __syncthreads();
    for (int i = t; i < n_b && i < CAP; i += 256) {
        u32 v = in_s[i];
        int p = atomicAdd(&cur[v >> 16], 1);
        if (p < CAP) out_s[p] = (u16)(v & 0xffffu);
    }
    __syncthreads();
    for (int i = t; i < n_b && i < CAP; i += 256) ebuf[base + i] = (u32)out_s[i];
}

// ---------- mean aggregation over bf16 rows ----------
// R5/R9-measured shape: 32 lanes/node (ushort4), 8 nodes/block, unroll x8.

__global__ __launch_bounds__(256)
void aggregate_bf16_kernel(const u16* __restrict__ xb, const int* __restrict__ off,
                           const u32* __restrict__ eidx, u16* __restrict__ meanb,
                           int n_nodes) {
    int node = blockIdx.x * 8 + (threadIdx.x >> 5);
    int lane = threadIdx.x & 31;
    if (node >= n_nodes) return;
    int beg = off[node], end = off[node + 1];
    int c = lane * 4;

    float ax = 0.f, ay = 0.f, az = 0.f, aw = 0.f;
    int e = beg;
    for (; e + 8 <= end; e += 8) {
        ushort4 v0 = *(const ushort4*)&xb[(size_t)eidx[e + 0] * D + c];
        ushort4 v1 = *(const ushort4*)&xb[(size_t)eidx[e + 1] * D + c];
        ushort4 v2 = *(const ushort4*)&xb[(size_t)eidx[e + 2] * D + c];
        ushort4 v3 = *(const ushort4*)&xb[(size_t)eidx[e + 3] * D + c];
        ushort4 v4 = *(const ushort4*)&xb[(size_t)eidx[e + 4] * D + c];
        ushort4 v5 = *(const ushort4*)&xb[(size_t)eidx[e + 5] * D + c];
        ushort4 v6 = *(const ushort4*)&xb[(size_t)eidx[e + 6] * D + c];
        ushort4 v7 = *(const ushort4*)&xb[(size_t)eidx[e + 7] * D + c];
        ax += bf2f(v0.x) + bf2f(v1.x) + bf2f(v2.x) + bf2f(v3.x)
            + bf2f(v4.x) + bf2f(v5.x) + bf2f(v6.x) + bf2f(v7.x);
        ay += bf2f(v0.y) + bf2f(v1.y) + bf2f(v2.y) + bf2f(v3.y)
            + bf2f(v4.y) + bf2f(v5.y) + bf2f(v6.y) + bf2f(v7.y);
        az += bf2f(v0.z) + bf2f(v1.z) + bf2f(v2.z) + bf2f(v3.z)
            + bf2f(v4.z) + bf2f(v5.z) + bf2f(v6.z) + bf2f(v7.z);
        aw += bf2f(v0.w) + bf2f(v1.w) + bf2f(v2.w) + bf2f(v3.w)
            + bf2f(v4.w) + bf2f(v5.w) + bf2f(v6.w) + bf2f(v7.w);
    }
    for (; e < end; ++e) {
        ushort4 v = *(const ushort4*)&xb[(size_t)eidx[e] * D + c];
        ax += bf2f(v.x); ay += bf2f(v.y); az += bf2f(v.z); aw += bf2f(v.w);
    }

    int deg = end - beg;
    float inv = 1.f / (float)(deg > 0 ? deg : 1);
    ushort4 o;
    o.x = f2bf(ax * inv); o.y = f2bf(ay * inv); o.z = f2bf(az * inv); o.w = f2bf(aw * inv);
    *(ushort4*)&meanb[(size_t)node * D + c] = o;
}

// ---------- linear via MFMA with LDS-staged W ----------
// out = relu([mean||self] @ Wcat^T + b). Block = 128 rows (8 waves x 16-row tiles).
// mfma_f32_16x16x32_bf16: A row=l&15, k=(l>>4)*8+j ; C/D col=l&15, row=(l>>4)*4+reg.

template<bool OUT_BF16>
__global__ __launch_bounds__(512)
void linear_mfma_kernel(const u16* __restrict__ Amean, const u16* __restrict__ Aself,
                        const u16* __restrict__ Wc, const float* __restrict__ bias,
                        void* __restrict__ outp, int N) {
    __shared__ u16 ws[128][136];   // 34816 B

    int t = threadIdx.x;
    int l = t & 63;
    int wv = t >> 6;               // 0..7
    int m0 = blockIdx.x * 128 + wv * 16;
    int lr = l & 15;
    int kg = (l >> 4) * 8;
    int rowA = m0 + lr;
    int rc = rowA < N ? rowA : N - 1;
    const u16* r1 = Amean + (size_t)rc * D;
    const u16* r2 = Aself + (size_t)rc * D;

    bf16x8 a[8];
#pragma unroll
    for (int kt = 0; kt < 4; ++kt) {
        a[kt]     = *(const bf16x8*)(r1 + kt * 32 + kg);   // k 0..127  (mean)
        a[kt + 4] = *(const bf16x8*)(r2 + kt * 32 + kg);   // k 128..255 (self)
    }

    f32x4 acc[8];
#pragma unroll
    for (int nt = 0; nt < 8; ++nt) acc[nt] = (f32x4){0.f, 0.f, 0.f, 0.f};

    for (int half = 0; half < 2; ++half) {
        if (half) __syncthreads();
        for (int i = t; i < 2048; i += 512) {
            int n = i >> 4, kq = i & 15;
            *(u16x8*)&ws[n][kq * 8] = *(const u16x8*)&Wc[(size_t)n * 256 + half * 128 + kq * 8];
        }
        __syncthreads();

#pragma unroll
        for (int nt = 0; nt < 8; ++nt) {
            bf16x8 b0 = *(const bf16x8*)&ws[nt * 16 + lr][0 * 32 + kg];
            bf16x8 b1 = *(const bf16x8*)&ws[nt * 16 + lr][1 * 32 + kg];
            bf16x8 b2 = *(const bf16x8*)&ws[nt * 16 + lr][2 * 32 + kg];
            bf16x8 b3 = *(const bf16x8*)&ws[nt * 16 + lr][3 * 32 + kg];
            acc[nt] = __builtin_amdgcn_mfma_f32_16x16x32_bf16(a[half * 4 + 0], b0, acc[nt], 0, 0, 0);
            acc[nt] = __builtin_amdgcn_mfma_f32_16x16x32_bf16(a[half * 4 + 1], b1, acc[nt], 0, 0, 0);
            acc[nt] = __builtin_amdgcn_mfma_f32_16x16x32_bf16(a[half * 4 + 2], b2, acc[nt], 0, 0, 0);
            acc[nt] = __builtin_amdgcn_mfma_f32_16x16x32_bf16(a[half * 4 + 3], b3, acc[nt], 0, 0, 0);
        }
    }

#pragma unroll
    for (int nt = 0; nt < 8; ++nt) {
        int col = nt * 16 + lr;
        float bb = bias[col];
#pragma unroll
        for (int j = 0; j < 4; ++j) {
            int r = m0 + (l >> 4) * 4 + j;
            if (r < N) {
                float v = fmaxf(acc[nt][j] + bb, 0.f);
                if (OUT_BF16) ((u16*)outp)[(size_t)r * D + col] = f2bf(v);
                else          ((float*)outp)[(size_t)r * D + col] = v;
            }
        }
    }
}

extern "C" void kernel_launch(void* const* d_in, const int* in_sizes, int n_in,
                              void* d_out, int out_size, void* d_ws, size_t ws_size,
                              hipStream_t stream) {
    const float* x   = (const float*)d_in[0];
    const int*   ei  = (const int*)d_in[1];
    const float* W1l = (const float*)d_in[2];
    const float* W1r = (const float*)d_in[3];
    const float* b1  = (const float*)d_in[4];
    const float* W2l = (const float*)d_in[5];
    const float* W2r = (const float*)d_in[6];
    const float* b2  = (const float*)d_in[7];
    float* out = (float*)d_out;

    const int N = in_sizes[0] / D;
    const int E = in_sizes[1] / 2;
    const int* src = ei;
    const int* dst = ei + E;
    const int NB = (N + BWID - 1) >> BW_LOG;       // 782 for N=50000 (<= NB_MAX)
    const int NBLK = (E + CHUNK - 1) / CHUNK;      // 391 for E=1.6M
    const int N4 = N * D / 4;
    const int XBLK = (N4 + 255) / 256;             // 6250

    // workspace layout: feature tables FIRST, 2MB-aligned (L2-set placement probe
    // for the unexplained R5-vs-R9 FETCH delta: 147 vs 209 MB, identical code).
    uintptr_t base_ = ((uintptr_t)d_ws + ((1u << 21) - 1)) & ~(uintptr_t)((1u << 21) - 1);
    char* wp_ = (char*)base_;
    auto alloc = [&](size_t bytes) { char* p = wp_; wp_ += (bytes + 63) & ~(size_t)63; return p; };
    u16* xb      = (u16*)alloc((size_t)N * D * 2);     // 12.8 MB @ 2MB boundary
    u16* meanb   = (u16*)alloc((size_t)N * D * 2);
    u16* h1b     = (u16*)alloc((size_t)N * D * 2);
    u16* wc1     = (u16*)alloc((size_t)128 * 256 * 2);
    u16* wc2     = (u16*)alloc((size_t)128 * 256 * 2);
    int* off_p   = (int*)alloc((size_t)(N + 1) * 4);
    int* bbase_p = (int*)alloc((size_t)(NB + 1) * 4);
    int* btot_p  = (int*)alloc((size_t)NB * 4);
    int* gh_p    = (int*)alloc((size_t)NB * NBLK * 4);
    u32* ebuf_p  = (u32*)alloc((size_t)E * 4);

    // fused prep: cvt_x + cvt_w + part_hist
    prep_kernel<<<XBLK + 256 + NBLK, 256, 0, stream>>>(
        x, xb, N4, W1l, W1r, W2l, W2r, wc1, wc2, dst, gh_p, E, NB, NBLK, XBLK);

    // CSR build
    part_scan1_kernel<<<NB, 64, 0, stream>>>(gh_p, btot_p, NBLK);
    part_scan2_kernel<<<1, 1024, 0, stream>>>(btot_p, bbase_p, NB, off_p + N);
    part_scatter_kernel<<<NBLK, 256, 0, stream>>>(src, dst, gh_p, bbase_p, ebuf_p, E, NB, NBLK);
    bucket_sort_kernel<<<NB, 256, 0, stream>>>(ebuf_p, bbase_p, off_p, N);

    // layer 1
    aggregate_bf16_kernel<<<(N + 7) / 8, 256, 0, stream>>>(xb, off_p, ebuf_p, meanb, N);
    linear_mfma_kernel<true><<<(N + 127) / 128, 512, 0, stream>>>(meanb, xb, wc1, b1, h1b, N);

    // layer 2
    aggregate_bf16_kernel<<<(N + 7) / 8, 256, 0, stream>>>(h1b, off_p, ebuf_p, meanb, N);
    linear_mfma_kernel<false><<<(N + 127) / 128, 512, 0, stream>>>(meanb, h1b, wc2, b2, out, N);
}

// Round 15
// 182.634 us; speedup vs baseline: 15.2189x; 1.0086x over previous
//
#include <hip/hip_runtime.h>

#define D 128
#define BW_LOG 6          // 64 nodes per bucket
#define BWID 64
#define CAP 4096          // max edges per bucket in LDS (mean ~2048, max ~2350)
#define CHUNK 4096        // edges per partition block (391 blocks -> occupancy)
#define NB_MAX 1024       // supports N <= 65536 (also required by 16-bit src packing)

typedef unsigned short u16;
typedef unsigned int u32;
typedef __attribute__((ext_vector_type(8))) short bf16x8;      // 8 bf16 (4 VGPRs)
typedef __attribute__((ext_vector_type(8))) unsigned short u16x8;
typedef __attribute__((ext_vector_type(4))) float f32x4;

__device__ __forceinline__ float bf2f(u16 h) { return __uint_as_float(((u32)h) << 16); }
__device__ __forceinline__ u16 f2bf(float f) {
    u32 u = __float_as_uint(f);
    u32 r = (u + 0x7fffu + ((u >> 16) & 1u)) >> 16;   // RNE
    return (u16)r;
}

// ---------- fused prep: cvt_x + cvt_w + part_hist in one block-partitioned launch ----------

__global__ __launch_bounds__(256)
void prep_kernel(const float* __restrict__ x, u16* __restrict__ xb, int n4,
                 const float* __restrict__ W1l, const float* __restrict__ W1r,
                 const float* __restrict__ W2l, const float* __restrict__ W2r,
                 u16* __restrict__ wc1, u16* __restrict__ wc2,
                 const int* __restrict__ dst, u16* __restrict__ gh,
                 int E, int nb, int nblk, int xblk) {
    __shared__ int h[NB_MAX];
    int b = blockIdx.x;
    int t = threadIdx.x;
    if (b < xblk) {
        int i = b * 256 + t;
        if (i < n4) {
            float4 v = ((const float4*)x)[i];
            ushort4 o;
            o.x = f2bf(v.x); o.y = f2bf(v.y); o.z = f2bf(v.z); o.w = f2bf(v.w);
            ((ushort4*)xb)[i] = o;
        }
        return;
    }
    if (b < xblk + 256) {
        int wb = b - xblk;
        int n = wb & 127;
        const float* Wl = (wb < 128) ? W1l : W2l;
        const float* Wr = (wb < 128) ? W1r : W2r;
        u16* wcat = (wb < 128) ? wc1 : wc2;
        float v = (t < 128) ? Wl[n * 128 + t] : Wr[n * 128 + t - 128];
        wcat[n * 256 + t] = f2bf(v);
        return;
    }
    int hb = b - xblk - 256;
    for (int i = t; i < nb; i += 256) h[i] = 0;
    __syncthreads();
    int lo = hb * CHUNK, hi = min(lo + CHUNK, E);
    for (int i = lo + t; i < hi; i += 256) atomicAdd(&h[dst[i] >> BW_LOG], 1);
    __syncthreads();
    for (int i = t; i < nb; i += 256) gh[(size_t)i * nblk + hb] = (u16)h[i];
}

// ---------- CSR build ----------

__global__ __launch_bounds__(64)
void part_scan1_kernel(u16* __restrict__ gh, int* __restrict__ btot, int nblk) {
    int k = blockIdx.x;
    int t = threadIdx.x;
    u16* row = gh + (size_t)k * nblk;
    int chunk = (nblk + 63) >> 6;
    int lo = t * chunk, hi = min(lo + chunk, nblk);
    int s = 0;
    for (int i = lo; i < hi; ++i) s += row[i];
    int incl = s;
#pragma unroll
    for (int d2 = 1; d2 < 64; d2 <<= 1) { int u = __shfl_up(incl, d2, 64); if (t >= d2) incl += u; }
    int excl = incl - s;
    for (int i = lo; i < hi; ++i) { int c = row[i]; row[i] = (u16)excl; excl += c; }
    if (t == 63) btot[k] = incl;
}

__global__ __launch_bounds__(1024)
void part_scan2_kernel(const int* __restrict__ btot, int* __restrict__ bbase,
                       int nb, int* __restrict__ offN) {
    __shared__ int ws[16];
    int t = threadIdx.x, lane = t & 63, wid = t >> 6;
    int v = (t < nb) ? btot[t] : 0;
    int incl = v;
#pragma unroll
    for (int d2 = 1; d2 < 64; d2 <<= 1) { int u = __shfl_up(incl, d2, 64); if (lane >= d2) incl += u; }
    if (lane == 63) ws[wid] = incl;
    __syncthreads();
    if (wid == 0) {
        int w = (lane < 16) ? ws[lane] : 0;
#pragma unroll
        for (int d2 = 1; d2 < 16; d2 <<= 1) { int u = __shfl_up(w, d2, 64); if (lane >= d2) w += u; }
        if (lane < 16) ws[lane] = w;
    }
    __syncthreads();
    int base = wid ? ws[wid - 1] : 0;
    int excl = base + incl - v;
    if (t < nb) bbase[t] = excl;
    if (t == nb - 1) { bbase[nb] = excl + v; *offN = excl + v; }
}

// record = (dst_local << 16) | src   (src < 65536)
__global__ __launch_bounds__(256)
void part_scatter_kernel(const int* __restrict__ src, const int* __restrict__ dst,
                         const u16* __restrict__ gh, const int* __restrict__ bbase,
                         u32* __restrict__ ebuf, int E, int nb, int nblk) {
    __shared__ int cur[NB_MAX];
    int b = blockIdx.x;
    for (int i = threadIdx.x; i < nb; i += 256)
        cur[i] = bbase[i] + (int)gh[(size_t)i * nblk + b];
    __syncthreads();
    int lo = b * CHUNK, hi = min(lo + CHUNK, E);
    for (int i = lo + threadIdx.x; i < hi; i += 256) {
        int d = dst[i];
        int p = atomicAdd(&cur[d >> BW_LOG], 1);
        ebuf[p] = ((u32)(d & (BWID - 1)) << 16) | (u32)src[i];
    }
}

// one block per bucket: LDS counting sort by dst_local; sorted src written as u16.
__global__ __launch_bounds__(256)
void bucket_sort_kernel(const u32* __restrict__ ebuf, const int* __restrict__ bbase,
                        u16* __restrict__ eidx16, int* __restrict__ off, int n_nodes) {
    __shared__ u32 in_s[CAP];
    __shared__ u16 out_s[CAP];
    __shared__ int hist[BWID], cur[BWID];
    int b = blockIdx.x;
    int base = bbase[b];
    int n_b = bbase[b + 1] - base;
    int t = threadIdx.x;
    if (t < BWID) hist[t] = 0;
    for (int i = t; i < n_b && i < CAP; i += 256) in_s[i] = ebuf[base + i];
    __syncthreads();
    for (int i = t; i < n_b && i < CAP; i += 256) atomicAdd(&hist[in_s[i] >> 16], 1);
    __syncthreads();
    if (t < BWID) {
        int s = hist[t];
        int incl = s;
#pragma unroll
        for (int d2 = 1; d2 < 64; d2 <<= 1) { int u = __shfl_up(incl, d2, 64); if (t >= d2) incl += u; }
        int excl = incl - s;
        cur[t] = excl;
        int node = (b << BW_LOG) + t;
        if (node < n_nodes) off[node] = base + excl;
    }
    __syncthreads();
    for (int i = t; i < n_b && i < CAP; i += 256) {
        u32 v = in_s[i];
        int p = atomicAdd(&cur[v >> 16], 1);
        if (p < CAP) out_s[p] = (u16)(v & 0xffffu);
    }
    __syncthreads();
    for (int i = t; i < n_b && i < CAP; i += 256) eidx16[base + i] = out_s[i];
}

// ---------- mean aggregation over bf16 rows ----------
// R5/R9/R14-measured shape: 32 lanes/node (ushort4), 8 nodes/block, unroll x8.
// Fill-path-bound: dur ~= FETCH / ~3 TB/s; FETCH depends on xb L2-set placement
// (2MB-aligned first-in-ws placement measured 147MB vs 209MB otherwise, R14).

__global__ __launch_bounds__(256)
void aggregate_bf16_kernel(const u16* __restrict__ xb, const int* __restrict__ off,
                           const u16* __restrict__ eidx, u16* __restrict__ meanb,
                           int n_nodes) {
    int node = blockIdx.x * 8 + (threadIdx.x >> 5);
    int lane = threadIdx.x & 31;
    if (node >= n_nodes) return;
    int beg = off[node], end = off[node + 1];
    int c = lane * 4;

    float ax = 0.f, ay = 0.f, az = 0.f, aw = 0.f;
    int e = beg;
    for (; e + 8 <= end; e += 8) {
        ushort4 v0 = *(const ushort4*)&xb[(size_t)eidx[e + 0] * D + c];
        ushort4 v1 = *(const ushort4*)&xb[(size_t)eidx[e + 1] * D + c];
        ushort4 v2 = *(const ushort4*)&xb[(size_t)eidx[e + 2] * D + c];
        ushort4 v3 = *(const ushort4*)&xb[(size_t)eidx[e + 3] * D + c];
        ushort4 v4 = *(const ushort4*)&xb[(size_t)eidx[e + 4] * D + c];
        ushort4 v5 = *(const ushort4*)&xb[(size_t)eidx[e + 5] * D + c];
        ushort4 v6 = *(const ushort4*)&xb[(size_t)eidx[e + 6] * D + c];
        ushort4 v7 = *(const ushort4*)&xb[(size_t)eidx[e + 7] * D + c];
        ax += bf2f(v0.x) + bf2f(v1.x) + bf2f(v2.x) + bf2f(v3.x)
            + bf2f(v4.x) + bf2f(v5.x) + bf2f(v6.x) + bf2f(v7.x);
        ay += bf2f(v0.y) + bf2f(v1.y) + bf2f(v2.y) + bf2f(v3.y)
            + bf2f(v4.y) + bf2f(v5.y) + bf2f(v6.y) + bf2f(v7.y);
        az += bf2f(v0.z) + bf2f(v1.z) + bf2f(v2.z) + bf2f(v3.z)
            + bf2f(v4.z) + bf2f(v5.z) + bf2f(v6.z) + bf2f(v7.z);
        aw += bf2f(v0.w) + bf2f(v1.w) + bf2f(v2.w) + bf2f(v3.w)
            + bf2f(v4.w) + bf2f(v5.w) + bf2f(v6.w) + bf2f(v7.w);
    }
    for (; e < end; ++e) {
        ushort4 v = *(const ushort4*)&xb[(size_t)eidx[e] * D + c];
        ax += bf2f(v.x); ay += bf2f(v.y); az += bf2f(v.z); aw += bf2f(v.w);
    }

    int deg = end - beg;
    float inv = 1.f / (float)(deg > 0 ? deg : 1);
    ushort4 o;
    o.x = f2bf(ax * inv); o.y = f2bf(ay * inv); o.z = f2bf(az * inv); o.w = f2bf(aw * inv);
    *(ushort4*)&meanb[(size_t)node * D + c] = o;
}

// ---------- linear via MFMA with LDS-staged W ----------
// out = relu([mean||self] @ Wcat^T + b). Block = 128 rows (8 waves x 16-row tiles).
// mfma_f32_16x16x32_bf16: A row=l&15, k=(l>>4)*8+j ; C/D col=l&15, row=(l>>4)*4+reg.

template<bool OUT_BF16>
__global__ __launch_bounds__(512)
void linear_mfma_kernel(const u16* __restrict__ Amean, const u16* __restrict__ Aself,
                        const u16* __restrict__ Wc, const float* __restrict__ bias,
                        void* __restrict__ outp, int N) {
    __shared__ u16 ws[128][136];   // 34816 B

    int t = threadIdx.x;
    int l = t & 63;
    int wv = t >> 6;               // 0..7
    int m0 = blockIdx.x * 128 + wv * 16;
    int lr = l & 15;
    int kg = (l >> 4) * 8;
    int rowA = m0 + lr;
    int rc = rowA < N ? rowA : N - 1;
    const u16* r1 = Amean + (size_t)rc * D;
    const u16* r2 = Aself + (size_t)rc * D;

    bf16x8 a[8];
#pragma unroll
    for (int kt = 0; kt < 4; ++kt) {
        a[kt]     = *(const bf16x8*)(r1 + kt * 32 + kg);   // k 0..127  (mean)
        a[kt + 4] = *(const bf16x8*)(r2 + kt * 32 + kg);   // k 128..255 (self)
    }

    f32x4 acc[8];
#pragma unroll
    for (int nt = 0; nt < 8; ++nt) acc[nt] = (f32x4){0.f, 0.f, 0.f, 0.f};

    for (int half = 0; half < 2; ++half) {
        if (half) __syncthreads();
        for (int i = t; i < 2048; i += 512) {
            int n = i >> 4, kq = i & 15;
            *(u16x8*)&ws[n][kq * 8] = *(const u16x8*)&Wc[(size_t)n * 256 + half * 128 + kq * 8];
        }
        __syncthreads();

#pragma unroll
        for (int nt = 0; nt < 8; ++nt) {
            bf16x8 b0 = *(const bf16x8*)&ws[nt * 16 + lr][0 * 32 + kg];
            bf16x8 b1 = *(const bf16x8*)&ws[nt * 16 + lr][1 * 32 + kg];
            bf16x8 b2 = *(const bf16x8*)&ws[nt * 16 + lr][2 * 32 + kg];
            bf16x8 b3 = *(const bf16x8*)&ws[nt * 16 + lr][3 * 32 + kg];
            acc[nt] = __builtin_amdgcn_mfma_f32_16x16x32_bf16(a[half * 4 + 0], b0, acc[nt], 0, 0, 0);
            acc[nt] = __builtin_amdgcn_mfma_f32_16x16x32_bf16(a[half * 4 + 1], b1, acc[nt], 0, 0, 0);
            acc[nt] = __builtin_amdgcn_mfma_f32_16x16x32_bf16(a[half * 4 + 2], b2, acc[nt], 0, 0, 0);
            acc[nt] = __builtin_amdgcn_mfma_f32_16x16x32_bf16(a[half * 4 + 3], b3, acc[nt], 0, 0, 0);
        }
    }

#pragma unroll
    for (int nt = 0; nt < 8; ++nt) {
        int col = nt * 16 + lr;
        float bb = bias[col];
#pragma unroll
        for (int j = 0; j < 4; ++j) {
            int r = m0 + (l >> 4) * 4 + j;
            if (r < N) {
                float v = fmaxf(acc[nt][j] + bb, 0.f);
                if (OUT_BF16) ((u16*)outp)[(size_t)r * D + col] = f2bf(v);
                else          ((float*)outp)[(size_t)r * D + col] = v;
            }
        }
    }
}

extern "C" void kernel_launch(void* const* d_in, const int* in_sizes, int n_in,
                              void* d_out, int out_size, void* d_ws, size_t ws_size,
                              hipStream_t stream) {
    const float* x   = (const float*)d_in[0];
    const int*   ei  = (const int*)d_in[1];
    const float* W1l = (const float*)d_in[2];
    const float* W1r = (const float*)d_in[3];
    const float* b1  = (const float*)d_in[4];
    const float* W2l = (const float*)d_in[5];
    const float* W2r = (const float*)d_in[6];
    const float* b2  = (const float*)d_in[7];
    float* out = (float*)d_out;

    const int N = in_sizes[0] / D;
    const int E = in_sizes[1] / 2;
    const int* src = ei;
    const int* dst = ei + E;
    const int NB = (N + BWID - 1) >> BW_LOG;       // 782 for N=50000 (<= NB_MAX)
    const int NBLK = (E + CHUNK - 1) / CHUNK;      // 391 for E=1.6M
    const int N4 = N * D / 4;
    const int XBLK = (N4 + 255) / 256;             // 6250

    // workspace layout: feature tables FIRST, 2MB-aligned (R14-measured: this
    // placement gives FETCH 147MB vs 209MB -> 51us vs 65us aggregates). New
    // buffers appended at END to preserve feature-table addresses exactly.
    uintptr_t base_ = ((uintptr_t)d_ws + ((1u << 21) - 1)) & ~(uintptr_t)((1u << 21) - 1);
    char* wp_ = (char*)base_;
    auto alloc = [&](size_t bytes) { char* p = wp_; wp_ += (bytes + 63) & ~(size_t)63; return p; };
    u16* xb      = (u16*)alloc((size_t)N * D * 2);     // 12.8 MB @ 2MB boundary
    u16* meanb   = (u16*)alloc((size_t)N * D * 2);
    u16* h1b     = (u16*)alloc((size_t)N * D * 2);
    u16* wc1     = (u16*)alloc((size_t)128 * 256 * 2);
    u16* wc2     = (u16*)alloc((size_t)128 * 256 * 2);
    int* off_p   = (int*)alloc((size_t)(N + 1) * 4);
    int* bbase_p = (int*)alloc((size_t)(NB + 1) * 4);
    int* btot_p  = (int*)alloc((size_t)NB * 4);
    u16* gh_p    = (u16*)alloc((size_t)NB * NBLK * 2);
    u32* ebuf_p  = (u32*)alloc((size_t)E * 4);
    u16* eidx16  = (u16*)alloc((size_t)E * 2);

    // fused prep: cvt_x + cvt_w + part_hist
    prep_kernel<<<XBLK + 256 + NBLK, 256, 0, stream>>>(
        x, xb, N4, W1l, W1r, W2l, W2r, wc1, wc2, dst, gh_p, E, NB, NBLK, XBLK);

    // CSR build
    part_scan1_kernel<<<NB, 64, 0, stream>>>(gh_p, btot_p, NBLK);
    part_scan2_kernel<<<1, 1024, 0, stream>>>(btot_p, bbase_p, NB, off_p + N);
    part_scatter_kernel<<<NBLK, 256, 0, stream>>>(src, dst, gh_p, bbase_p, ebuf_p, E, NB, NBLK);
    bucket_sort_kernel<<<NB, 256, 0, stream>>>(ebuf_p, bbase_p, eidx16, off_p, N);

    // layer 1
    aggregate_bf16_kernel<<<(N + 7) / 8, 256, 0, stream>>>(xb, off_p, eidx16, meanb, N);
    linear_mfma_kernel<true><<<(N + 127) / 128, 512, 0, stream>>>(meanb, xb, wc1, b1, h1b, N);

    // layer 2
    aggregate_bf16_kernel<<<(N + 7) / 8, 256, 0, stream>>>(h1b, off_p, eidx16, meanb, N);
    linear_mfma_kernel<false><<<(N + 127) / 128, 512, 0, stream>>>(meanb, h1b, wc2, b2, out, N);
}